// Round 2
// baseline (199.086 us; speedup 1.0000x reference)
//
#include <hip/hip_runtime.h>

typedef __attribute__((ext_vector_type(8))) short s16x8;
typedef __attribute__((ext_vector_type(4))) short s16x4;
typedef __attribute__((ext_vector_type(4))) float f32x4;

namespace {
constexpr int kCS = 256, kDH = 64, kDS = 128, kBH = 512;
constexpr float kAlpha = 0.5f;

// y-path LDS byte offsets (total 30 KB -> 5 blocks/CU, 20 waves/CU)
constexpr int OFF_AC   = 0;                  // ac: 256 f32
constexpr int OFF_ENEG = 1024;               // eneg: 256 f32
constexpr int OFF_B    = 2048;               // Bhi [32][128] s16 (8KB); aliased by C fp32 bounce (16KB) and HThi half
constexpr int OFF_BLO  = OFF_B + 8192;       // Blo / HTlo
constexpr int OFF_XT   = OFF_B + 16384;      // XThi [64][32] s16 (4KB)
constexpr int OFF_XTLO = OFF_XT + 4096;      // XTlo
constexpr int OFF_S    = OFF_XTLO + 4096;    // S~hi per-wave [16][32] s16, 4 waves (4KB); cumsum partials early
constexpr int LDS_BYTES = OFF_S + 4096;      // 30720

// hend-path LDS view (25.7KB, fits in same block)
constexpr int HOFF_AC = 0;                   // ac: 256 f32
constexpr int HOFF_W  = 1024;                // wsh: 32 f32
constexpr int HOFF_XS = 2048;                // xs [32][64] f32 (8KB)
constexpr int HOFF_BS = 2048 + 8192;         // bs [32][128] f32 (16KB)
}

union F4 { float4 v; float f[4]; };

// packed f32x2 -> bf16x2 (RNE), 1 VALU inst
__device__ __forceinline__ unsigned cvt_pk_bf16(float a, float b) {
  unsigned r;
  asm("v_cvt_pk_bf16_f32 %0, %1, %2" : "=v"(r) : "v"(a), "v"(b));
  return r;
}

__device__ __forceinline__ unsigned short bf16_1(float x) {
  return (unsigned short)cvt_pk_bf16(x, x);
}

__device__ __forceinline__ void split8(const float* v, s16x8& hi, s16x8& lo) {
  unsigned* hp = (unsigned*)&hi;
  unsigned* lp = (unsigned*)&lo;
#pragma unroll
  for (int p = 0; p < 4; ++p) {
    float a = v[2 * p], b = v[2 * p + 1];
    unsigned h = cvt_pk_bf16(a, b);
    float ra = a - __uint_as_float(h << 16);
    float rb = b - __uint_as_float(h & 0xFFFF0000u);
    hp[p] = h;
    lp[p] = cvt_pk_bf16(ra, rb);
  }
}

__device__ __forceinline__ void split4(const float* v, s16x4& hi, s16x4& lo) {
  unsigned* hp = (unsigned*)&hi;
  unsigned* lp = (unsigned*)&lo;
#pragma unroll
  for (int p = 0; p < 2; ++p) {
    float a = v[2 * p], b = v[2 * p + 1];
    unsigned h = cvt_pk_bf16(a, b);
    float ra = a - __uint_as_float(h << 16);
    float rb = b - __uint_as_float(h & 0xFFFF0000u);
    hp[p] = h;
    lp[p] = cvt_pk_bf16(ra, rb);
  }
}

// Fused launch: blocks [0, 512) do h_end, blocks [512, 2560) do Y.
// h_end blocks are VALU+HBM heavy and overlap the latency-bound Y blocks.
__global__ __launch_bounds__(256, 5) void fused_kernel(
    const float* __restrict__ Xg, const float* __restrict__ Ag,
    const float* __restrict__ Bg, const float* __restrict__ Cg,
    const float* __restrict__ Hg, float* __restrict__ Yg,
    float* __restrict__ hend, float* __restrict__ dtot) {
  __shared__ __align__(16) char smem[LDS_BYTES];
  const int bidx = blockIdx.x;
  const int tid = threadIdx.x;
  const int lane = tid & 63;
  const int w = tid >> 6;

  if (bidx < kBH) {
    // ======================= h_end path =======================
    const int bh = bidx;
    float* ac  = (float*)(smem + HOFF_AC);
    float* wsh = (float*)(smem + HOFF_W);
    float (*xs)[kDH] = (float(*)[kDH])(smem + HOFF_XS);
    float (*bs)[kDS] = (float(*)[kDS])(smem + HOFF_BS);

    const float* Xb = Xg + (size_t)bh * kCS * kDH;
    const float* Ab = Ag + (size_t)bh * kCS;
    const float* Bb = Bg + (size_t)bh * kCS * kDS;
    const float* Hb = Hg + (size_t)bh * kDS * kDH;
    float* Ob = hend + (size_t)bh * kDS * kDH;

    // shuffle-scan cumsum
    {
      float v = Ab[tid];
#pragma unroll
      for (int off = 1; off < 64; off <<= 1) {
        float t = __shfl_up(v, off);
        if (lane >= off) v += t;
      }
      if (lane == 63) wsh[w] = v;
      __syncthreads();
      float base = 0.f;
#pragma unroll
      for (int k = 0; k < 4; ++k)
        if (k < w) base += wsh[k];
      ac[tid] = v + base;
      __syncthreads();
    }
    const float alast = ac[kCS - 1];
    if (tid == 0) dtot[bh] = __expf(alast);

    const int dcol = tid & 15;
    const int srow = tid >> 4;
    float4 acc[8];
#pragma unroll
    for (int m = 0; m < 8; ++m) acc[m] = make_float4(0.f, 0.f, 0.f, 0.f);

    for (int t0 = 0; t0 < kCS; t0 += 32) {
      __syncthreads();
      if (tid < 32) wsh[tid] = __expf(alast - ac[t0 + tid]);
      __syncthreads();
#pragma unroll
      for (int k = 0; k < 2; ++k) {
        int fid = k * 256 + tid;
        int r = fid >> 4, c = fid & 15;
        float4 xv = *(const float4*)&Xb[(size_t)(t0 + r) * kDH + c * 4];
        float wv = wsh[r];
        xv.x *= wv; xv.y *= wv; xv.z *= wv; xv.w *= wv;
        *(float4*)&xs[r][c * 4] = xv;
      }
#pragma unroll
      for (int k = 0; k < 4; ++k) {
        int fid = k * 256 + tid;
        int r = fid >> 5, c = fid & 31;
        *(float4*)&bs[r][c * 4] = *(const float4*)&Bb[(size_t)(t0 + r) * kDS + c * 4];
      }
      __syncthreads();
      for (int tt = 0; tt < 32; ++tt) {
        float4 xv = *(const float4*)&xs[tt][dcol * 4];
#pragma unroll
        for (int m = 0; m < 8; ++m) {
          float b = bs[tt][srow + 16 * m];
          acc[m].x = fmaf(b, xv.x, acc[m].x);
          acc[m].y = fmaf(b, xv.y, acc[m].y);
          acc[m].z = fmaf(b, xv.z, acc[m].z);
          acc[m].w = fmaf(b, xv.w, acc[m].w);
        }
      }
    }
    const float dscale = kAlpha * __expf(alast);
    const float sc = 1.f - kAlpha;
#pragma unroll
    for (int m = 0; m < 8; ++m) {
      int s = srow + 16 * m;
      float4 hv = *(const float4*)&Hb[(size_t)s * kDH + dcol * 4];
      float4 o;
      o.x = dscale * hv.x + sc * acc[m].x;
      o.y = dscale * hv.y + sc * acc[m].y;
      o.z = dscale * hv.z + sc * acc[m].z;
      o.w = dscale * hv.w + sc * acc[m].w;
      *(float4*)&Ob[(size_t)s * kDH + dcol * 4] = o;
    }
    return;
  }

  // ======================= Y path =======================
  const int idx = bidx - kBH;
  const int it = 3 - (idx >> 9);   // heavy tiles dispatched first
  const int bh = idx & 511;

  float* ac   = (float*)(smem + OFF_AC);
  float* eneg = (float*)(smem + OFF_ENEG);
  short* Bhi  = (short*)(smem + OFF_B);
  short* Blo  = (short*)(smem + OFF_BLO);
  short* XThi = (short*)(smem + OFF_XT);
  short* XTlo = (short*)(smem + OFF_XTLO);
  short* Sall = (short*)(smem + OFF_S);
  float* Cb   = (float*)(smem + OFF_B);   // fp32 bounce, aliases Bhi+Blo (16KB)
  short* HThi = Bhi;                      // h_prev^T half-planes alias B planes
  short* HTlo = Blo;

  const int fr = lane & 15;   // fragment free-index (A row / B col / D col)
  const int fg = lane >> 4;   // fragment k-group

  const float* Xb = Xg + (size_t)bh * kCS * kDH;
  const float* Ab = Ag + (size_t)bh * kCS;
  const float* Bb = Bg + (size_t)bh * kCS * kDS;
  const float* Cg_b = Cg + (size_t)bh * kCS * kDS;
  const float* Hb = Hg + (size_t)bh * kDS * kDH;
  float* Yb = Yg + (size_t)bh * kCS * kDH;

  // ---- cumsum via wave shuffle scan
  {
    float v = Ab[tid];
#pragma unroll
    for (int off = 1; off < 64; off <<= 1) {
      float t = __shfl_up(v, off);
      if (lane >= off) v += t;
    }
    float* wsum = (float*)(smem + OFF_S);
    if (lane == 63) wsum[w] = v;
    __syncthreads();
    float base = 0.f;
#pragma unroll
    for (int k = 0; k < 4; ++k)
      if (k < w) base += wsum[k];
    const float a = v + base;
    ac[tid] = a;
    eneg[tid] = __expf(-a);
    __syncthreads();
  }

  const int i0 = it * 64;
  float eaci[4];
#pragma unroll
  for (int r = 0; r < 4; ++r) eaci[r] = __expf(ac[i0 + w * 16 + fg * 4 + r]);

  // ---- C bounce in two 32-row halves: global (coalesced) -> LDS fp32 (16B-block XOR swizzle)
  s16x8 chi[4], clo[4];
#pragma unroll
  for (int m = 0; m < 2; ++m) {
#pragma unroll
    for (int k = 0; k < 4; ++k) {
      int fid = k * 256 + tid;
      int r = fid >> 5, c = fid & 31;
      *(float4*)&Cb[r * 128 + ((c ^ (r & 7)) << 2)] =
          *(const float4*)&Cg_b[(size_t)(i0 + m * 32 + r) * kDS + c * 4];
    }
    __syncthreads();
    if ((w >> 1) == m) {
      const int lrow = (w & 1) * 16 + fr;
      const float* crow = &Cb[lrow * 128];
      const int r7 = lrow & 7;
#pragma unroll
      for (int kc = 0; kc < 4; ++kc) {
        const int c0 = kc * 8 + fg * 2;
        F4 u0, u1;
        u0.v = *(const float4*)&crow[(c0 ^ r7) << 2];
        u1.v = *(const float4*)&crow[((c0 + 1) ^ r7) << 2];
        float v[8] = {u0.f[0], u0.f[1], u0.f[2], u0.f[3], u1.f[0], u1.f[1], u1.f[2], u1.f[3]};
        split8(v, chi[kc], clo[kc]);
      }
    }
    __syncthreads();
  }

  f32x4 yacc[4];
#pragma unroll
  for (int n = 0; n < 4; ++n)
#pragma unroll
    for (int r = 0; r < 4; ++r) yacc[n][r] = 0.f;

  short* Sp = Sall + w * 512;  // per-wave S~ plane [16][32]

  const int jt_n = 2 * it + 2;

  // prefetch registers for next tile (T14 async split: issue early, consume next iter)
  F4 pb[4];
  float px[8];
  {
    const int row = (tid >> 4);
    const int g = tid & 15;
    pb[0].v = *(const float4*)&Bb[(size_t)row * kDS + g * 8];
    pb[1].v = *(const float4*)&Bb[(size_t)row * kDS + g * 8 + 4];
    pb[2].v = *(const float4*)&Bb[(size_t)(16 + row) * kDS + g * 8];
    pb[3].v = *(const float4*)&Bb[(size_t)(16 + row) * kDS + g * 8 + 4];
#pragma unroll
    for (int s = 0; s < 8; ++s) px[s] = Xb[(size_t)(w * 8 + s) * kDH + lane];
  }

  for (int jt = 0; jt < jt_n; ++jt) {
    // ---- split+write current tile from prefetch regs
#pragma unroll
    for (int k = 0; k < 2; ++k) {
      const int row = k * 16 + (tid >> 4);
      const int g = tid & 15;
      float v[8] = {pb[2 * k].f[0], pb[2 * k].f[1], pb[2 * k].f[2], pb[2 * k].f[3],
                    pb[2 * k + 1].f[0], pb[2 * k + 1].f[1], pb[2 * k + 1].f[2], pb[2 * k + 1].f[3]};
      s16x8 h8, l8;
      split8(v, h8, l8);
      const int col = (g ^ (row & 7)) * 8;
      *(s16x8*)&Bhi[row * 128 + col] = h8;
      *(s16x8*)&Blo[row * 128 + col] = l8;
    }
    {
      const int d = lane;
      s16x8 h8, l8;
      split8(px, h8, l8);
      const int off = d * 32 + ((w ^ ((d >> 2) & 3)) << 3);
      *(s16x8*)&XThi[off] = h8;
      *(s16x8*)&XTlo[off] = l8;
    }
    // ---- issue next tile's loads (latency hides under barrier+MFMA phase)
    if (jt + 1 < jt_n) {
      const int j0n = (jt + 1) * 32;
      const int row = (tid >> 4);
      const int g = tid & 15;
      pb[0].v = *(const float4*)&Bb[(size_t)(j0n + row) * kDS + g * 8];
      pb[1].v = *(const float4*)&Bb[(size_t)(j0n + row) * kDS + g * 8 + 4];
      pb[2].v = *(const float4*)&Bb[(size_t)(j0n + 16 + row) * kDS + g * 8];
      pb[3].v = *(const float4*)&Bb[(size_t)(j0n + 16 + row) * kDS + g * 8 + 4];
#pragma unroll
      for (int s = 0; s < 8; ++s) px[s] = Xb[(size_t)(j0n + w * 8 + s) * kDH + lane];
    }
    __syncthreads();

    const int j0 = jt * 32;
    // ---- S = C·B^T  (split: Chi·Bhi + Chi·Blo + Clo·Bhi)
    f32x4 s[2];
#pragma unroll
    for (int n = 0; n < 2; ++n) {
#pragma unroll
      for (int r = 0; r < 4; ++r) s[n][r] = 0.f;
      const int jrow = n * 16 + fr;
      const short* bph = &Bhi[jrow * 128];
      const short* bpl = &Blo[jrow * 128];
#pragma unroll
      for (int kc = 0; kc < 4; ++kc) {
        const int phys = ((4 * kc + fg) ^ (jrow & 7)) * 8;
        s16x8 b8 = *(const s16x8*)&bph[phys];
        s16x8 l8 = *(const s16x8*)&bpl[phys];
        s[n] = __builtin_amdgcn_mfma_f32_16x16x32_bf16(chi[kc], b8, s[n], 0, 0, 0);
        s[n] = __builtin_amdgcn_mfma_f32_16x16x32_bf16(chi[kc], l8, s[n], 0, 0, 0);
        s[n] = __builtin_amdgcn_mfma_f32_16x16x32_bf16(clo[kc], b8, s[n], 0, 0, 0);
      }
    }
    // ---- mask + decay, write S~ (bf16 hi) to per-wave plane (block-XOR swizzle)
#pragma unroll
    for (int n = 0; n < 2; ++n) {
      const int jg = j0 + n * 16 + fr;
      const float enj = eneg[jg];
#pragma unroll
      for (int r = 0; r < 4; ++r) {
        const int iwl = fg * 4 + r;
        const int ig = i0 + w * 16 + iwl;
        float sv = s[n][r] * eaci[r] * enj;
        sv = (jg <= ig) ? sv : 0.f;
        Sp[iwl * 32 + (((n * 2 + (fr >> 3)) ^ fg) << 3) + (fr & 7)] = (short)bf16_1(sv);
      }
    }
    // ---- PV: Y += S~ · X   (S~hi·Xhi + S~hi·Xlo)
    {
      s16x8 sa = *(const s16x8*)&Sp[fr * 32 + ((fg ^ (fr >> 2)) << 3)];
#pragma unroll
      for (int n = 0; n < 4; ++n) {
        const int drow = n * 16 + fr;
        const int px2 = (fg ^ ((drow >> 2) & 3)) << 3;
        s16x8 xh = *(const s16x8*)&XThi[drow * 32 + px2];
        s16x8 xl = *(const s16x8*)&XTlo[drow * 32 + px2];
        yacc[n] = __builtin_amdgcn_mfma_f32_16x16x32_bf16(sa, xh, yacc[n], 0, 0, 0);
        yacc[n] = __builtin_amdgcn_mfma_f32_16x16x32_bf16(sa, xl, yacc[n], 0, 0, 0);
      }
    }
    __syncthreads();
  }

  // ---- Yh = C · h_prev in two s-halves (HT half-plane aliases B planes, 16KB)
  f32x4 yh[4];
#pragma unroll
  for (int n = 0; n < 4; ++n)
#pragma unroll
    for (int r = 0; r < 4; ++r) yh[n][r] = 0.f;

#pragma unroll
  for (int m = 0; m < 2; ++m) {
    // stage h_prev^T half: h[64s][64d] -> HT[d][s_local] hi/lo
    {
      const int dd = tid & 15, tt = tid >> 4;
      F4 hr[4];
#pragma unroll
      for (int r = 0; r < 4; ++r)
        hr[r].v = *(const float4*)&Hb[(size_t)(m * 64 + tt * 4 + r) * kDH + dd * 4];
#pragma unroll
      for (int c = 0; c < 4; ++c) {
        const int d = dd * 4 + c;
        float v4[4] = {hr[0].f[c], hr[1].f[c], hr[2].f[c], hr[3].f[c]};
        s16x4 h4, l4;
        split4(v4, h4, l4);
        const int off = d * 64 + (((tt >> 1) ^ (d & 7)) << 3) + ((tt & 1) << 2);
        *(s16x4*)&HThi[off] = h4;
        *(s16x4*)&HTlo[off] = l4;
      }
    }
    __syncthreads();
#pragma unroll
    for (int kcl = 0; kcl < 2; ++kcl) {
      const int kc = m * 2 + kcl;
#pragma unroll
      for (int n = 0; n < 4; ++n) {
        const int drow = n * 16 + fr;
        const int phys = ((4 * kcl + fg) ^ (drow & 7)) * 8;
        s16x8 hh = *(const s16x8*)&HThi[drow * 64 + phys];
        s16x8 hl = *(const s16x8*)&HTlo[drow * 64 + phys];
        yh[n] = __builtin_amdgcn_mfma_f32_16x16x32_bf16(chi[kc], hh, yh[n], 0, 0, 0);
        yh[n] = __builtin_amdgcn_mfma_f32_16x16x32_bf16(chi[kc], hl, yh[n], 0, 0, 0);
        yh[n] = __builtin_amdgcn_mfma_f32_16x16x32_bf16(clo[kc], hh, yh[n], 0, 0, 0);
      }
    }
    if (m == 0) __syncthreads();  // before half-1 staging overwrites HT
  }

  // ---- epilogue: Y = (1-a)*Y_intra + a*exp(ac_i)*Yh
#pragma unroll
  for (int n = 0; n < 4; ++n) {
#pragma unroll
    for (int r = 0; r < 4; ++r) {
      const int ig = i0 + w * 16 + fg * 4 + r;
      const int d = n * 16 + fr;
      Yb[(size_t)ig * kDH + d] = (1.f - kAlpha) * yacc[n][r] + (kAlpha * eaci[r]) * yh[n][r];
    }
  }
}

extern "C" void kernel_launch(void* const* d_in, const int* in_sizes, int n_in,
                              void* d_out, int out_size, void* d_ws, size_t ws_size,
                              hipStream_t stream) {
  const float* X = (const float*)d_in[0];
  const float* A = (const float*)d_in[1];
  const float* B = (const float*)d_in[2];
  const float* C = (const float*)d_in[3];
  const float* H = (const float*)d_in[4];
  float* out = (float*)d_out;
  float* Y = out;
  float* hend = Y + (size_t)kBH * kCS * kDH;
  float* dt = hend + (size_t)kBH * kDS * kDH;

  fused_kernel<<<kBH + 2048, 256, 0, stream>>>(X, A, B, C, H, Y, hend, dt);
}